// Round 13
// baseline (90.822 us; speedup 1.0000x reference)
//
#include <hip/hip_runtime.h>
#include <hip/hip_bf16.h>

// Shapes (fixed): B=8, E=768, C=256, CI=128, H=W=14, UP=4 -> H2=W2=56, N=3136, NQ=196
#define B_ 8
#define E_ 768
#define C_ 256
#define CI_ 128
#define NQ_ 196
#define N_ 3136

typedef short bf16x8 __attribute__((ext_vector_type(8)));
typedef float f32x4 __attribute__((ext_vector_type(4)));

__device__ __forceinline__ ushort f2bf(float x) {
    union { float f; uint u; } v; v.f = x;
    uint r = v.u + 0x7FFFu + ((v.u >> 16) & 1u);   // RNE
    return (ushort)(r >> 16);
}
__device__ __forceinline__ uint pack2(float a, float b) {
    return (uint)f2bf(a) | ((uint)f2bf(b) << 16);
}

// ================= K01: transpose (0..1567) | weight conv+zero (1568..1823)
//                        | k1a proj with inline Wp conversion (1824..2079) ======
__global__ __launch_bounds__(256) void k01(
    const float* __restrict__ x_cnn, ushort* __restrict__ xT,
    const float* __restrict__ Wth, const float* __restrict__ Wg,
    const float* __restrict__ Wph, const float* __restrict__ Wz,
    const float* __restrict__ x_t, const float* __restrict__ Wp,
    const float* __restrict__ bp, const float* __restrict__ g1, const float* __restrict__ b1,
    const float* __restrict__ rm1, const float* __restrict__ rv1,
    ushort* __restrict__ Wcomb, ushort* __restrict__ Wph_bf, ushort* __restrict__ Wz_bf,
    float* __restrict__ y_ws, float* __restrict__ rowsum, ushort* __restrict__ xact)
{
    __shared__ float Xs[64][68];
    __shared__ ushort Al[32 * 40];
    __shared__ ushort Bl[64 * 40];
    int bx = blockIdx.x;
    int t = threadIdx.x;

    if (bx >= 1824) {
        // ---- k1a: xact = relu(BN(x_t @ Wp^T)), 32q x 64c tiles, K=768 ----
        int bx2 = bx - 1824;
        int b = bx2 & 7; int rest = bx2 >> 3;
        int mt = rest & 7, nt = rest >> 3;
        int q0 = mt * 32, c0 = nt * 64;
        int lane = t & 63, w = t >> 6;

        int arow = t >> 3, ac4 = t & 7;
        bool arow_ok = (q0 + arow) < NQ_;
        const float* gax = x_t + (size_t)b * 197 * 768 + (size_t)(1 + q0 + arow) * 768 + ac4 * 4;
        int brow = t >> 2, bc = t & 3;
        const float* gbf = Wp + (size_t)(c0 + brow) * 768 + bc * 8;
        float binv = g1[c0 + brow] * rsqrtf(rv1[c0 + brow] + 1e-6f);
        ushort* la = &Al[arow * 40 + ac4 * 4];
        ushort* lb = &Bl[brow * 40 + bc * 8];

        f32x4 acc0 = (f32x4){0.f, 0.f, 0.f, 0.f};
        f32x4 acc1 = (f32x4){0.f, 0.f, 0.f, 0.f};
        int am = (lane & 15) * 40 + (lane >> 4) * 8;
        int bn = (w * 16 + (lane & 15)) * 40 + (lane >> 4) * 8;

        uint2 aw; aw.x = 0; aw.y = 0;
        if (arow_ok) { float4 x0 = *(const float4*)(gax); aw.x = pack2(x0.x, x0.y); aw.y = pack2(x0.z, x0.w); }
        uint4 bw;
        {
            float4 u = *(const float4*)(gbf), v = *(const float4*)(gbf + 4);
            bw.x = pack2(u.x * binv, u.y * binv); bw.y = pack2(u.z * binv, u.w * binv);
            bw.z = pack2(v.x * binv, v.y * binv); bw.w = pack2(v.z * binv, v.w * binv);
        }

        for (int ks = 0; ks < 24; ++ks) {
            __syncthreads();
            *(uint2*)la = aw;
            *(uint4*)lb = bw;
            __syncthreads();
            if (ks + 1 < 24) {
                aw.x = 0; aw.y = 0;
                if (arow_ok) {
                    float4 x0 = *(const float4*)(gax + (ks + 1) * 32);
                    aw.x = pack2(x0.x, x0.y); aw.y = pack2(x0.z, x0.w);
                }
                float4 u = *(const float4*)(gbf + (ks + 1) * 32);
                float4 v = *(const float4*)(gbf + (ks + 1) * 32 + 4);
                bw.x = pack2(u.x * binv, u.y * binv); bw.y = pack2(u.z * binv, u.w * binv);
                bw.z = pack2(v.x * binv, v.y * binv); bw.w = pack2(v.z * binv, v.w * binv);
            }
            bf16x8 af0 = *(const bf16x8*)(&Al[am]);
            bf16x8 af1 = *(const bf16x8*)(&Al[am + 16 * 40]);
            bf16x8 bfv = *(const bf16x8*)(&Bl[bn]);
            acc0 = __builtin_amdgcn_mfma_f32_16x16x32_bf16(af0, bfv, acc0, 0, 0, 0);
            acc1 = __builtin_amdgcn_mfma_f32_16x16x32_bf16(af1, bfv, acc1, 0, 0, 0);
        }

        int r4 = (lane >> 4) * 4;
        int cn = lane & 15;
        int c = c0 + w * 16 + cn;
        float inv1 = g1[c] * rsqrtf(rv1[c] + 1e-6f);
        float badd = bp[c] * inv1 + b1[c] - rm1[c] * inv1;
        #pragma unroll
        for (int r = 0; r < 4; ++r) {
            float v0 = fmaxf(acc0[r] + badd, 0.0f);
            float v1 = fmaxf(acc1[r] + badd, 0.0f);
            xact[((size_t)((b << 8) + q0 + r4 + r)) * 256 + c] = f2bf(v0);
            xact[((size_t)((b << 8) + q0 + 16 + r4 + r)) * 256 + c] = f2bf(v1);
        }
        return;
    }
    if (bx >= 1568) {
        // ---- weight conv + zeroing ----
        int idx = (bx - 1568) * 256 + t;          // 0..65535
        int o = idx >> 8, c = idx & 255;
        float v = (o < 128) ? Wth[o * 256 + c] : Wg[(o - 128) * 256 + c];
        Wcomb[idx] = f2bf(v);
        if (idx < 32768) Wph_bf[idx] = f2bf(Wph[idx]);
        if (idx < 32768) Wz_bf[idx] = f2bf(Wz[idx]);
        if (idx < 2048) rowsum[idx] = 0.0f;
        for (int i = idx; i < B_ * NQ_ * CI_; i += 65536) y_ws[i] = 0.0f;
        return;
    }
    // ---- x_cnn transpose -> xT bf16 ----
    int b = bx & 7; int rest = bx >> 3;
    int ct = rest & 3, nt = rest >> 2;            // ct 0..3, nt 0..48
    int c0 = ct * 64, n0 = nt * 64;
    #pragma unroll
    for (int rr = 0; rr < 4; ++rr) {
        int idx = t + rr * 256;                   // 0..1023
        int c = idx >> 4, n4 = idx & 15;
        float4 v = *(const float4*)(x_cnn + ((size_t)(b * C_) + c0 + c) * N_ + n0 + n4 * 4);
        *(float4*)(&Xs[c][n4 * 4]) = v;
    }
    __syncthreads();
    int n = t & 63, cc = t >> 6;                  // cc 0..3 (16 c each)
    ushort vals[16];
    #pragma unroll
    for (int j = 0; j < 16; ++j)
        vals[j] = f2bf(Xs[cc * 16 + j][n]);
    ushort* outp = xT + ((size_t)(b * N_) + n0 + n) * 256 + c0 + cc * 16;
    *(uint4*)(outp) = *(const uint4*)(&vals[0]);
    *(uint4*)(outp + 8) = *(const uint4*)(&vals[8]);
}

// ================= K12: k2 theta/g GEMM (0..783) | k1b phi GEMM (784..847) =====
__global__ __launch_bounds__(256) void k12(
    const ushort* __restrict__ Wcomb, const float* __restrict__ bth, const float* __restrict__ bg,
    const ushort* __restrict__ xT, ushort* __restrict__ thT, ushort* __restrict__ gT,
    const ushort* __restrict__ xact, const ushort* __restrict__ Wph_bf,
    const float* __restrict__ bph, ushort* __restrict__ phi_bf)
{
    __shared__ ushort Al[128 * 40];
    __shared__ ushort Bl[64 * 40];
    int t = threadIdx.x;
    int lane = t & 63, w = t >> 6;

    if (blockIdx.x >= 784) {
        // ---- k1b: phi = xact @ Wph^T + bph, 64q x 64i tiles, K=256 ----
        int bx2 = blockIdx.x - 784;
        int b = bx2 & 7; int rest = bx2 >> 3;
        int mt = rest & 3, nt = rest >> 2;
        int q0 = mt * 64, i0 = nt * 64;
        int wm = w >> 1, wn = w & 1;
        int row = t >> 2, chunk = t & 3;

        const ushort* ga = xact + ((size_t)((b << 8) + q0 + row)) * 256 + chunk * 8;
        const ushort* gb = Wph_bf + (size_t)(i0 + row) * 256 + chunk * 8;
        ushort* la = &Al[row * 40 + chunk * 8];
        ushort* lb = &Bl[row * 40 + chunk * 8];

        f32x4 acc[2][2];
        #pragma unroll
        for (int a = 0; a < 2; ++a)
            #pragma unroll
            for (int bb = 0; bb < 2; ++bb) acc[a][bb] = (f32x4){0.f, 0.f, 0.f, 0.f};

        int am = (wm * 32 + (lane & 15)) * 40 + (lane >> 4) * 8;
        int bn = (wn * 32 + (lane & 15)) * 40 + (lane >> 4) * 8;

        uint4 aw = *(const uint4*)(ga);
        uint4 bw = *(const uint4*)(gb);
        for (int ks = 0; ks < 8; ++ks) {
            __syncthreads();
            *(uint4*)la = aw;
            *(uint4*)lb = bw;
            __syncthreads();
            if (ks + 1 < 8) {
                aw = *(const uint4*)(ga + (ks + 1) * 32);
                bw = *(const uint4*)(gb + (ks + 1) * 32);
            }
            bf16x8 af[2], bfv[2];
            #pragma unroll
            for (int fm = 0; fm < 2; ++fm) af[fm] = *(const bf16x8*)(&Al[am + fm * 16 * 40]);
            #pragma unroll
            for (int fn = 0; fn < 2; ++fn) bfv[fn] = *(const bf16x8*)(&Bl[bn + fn * 16 * 40]);
            #pragma unroll
            for (int fm = 0; fm < 2; ++fm)
                #pragma unroll
                for (int fn = 0; fn < 2; ++fn)
                    acc[fm][fn] = __builtin_amdgcn_mfma_f32_16x16x32_bf16(af[fm], bfv[fn], acc[fm][fn], 0, 0, 0);
        }

        int r4 = (lane >> 4) * 4;
        int cn = lane & 15;
        #pragma unroll
        for (int fn = 0; fn < 2; ++fn) {
            int i = i0 + wn * 32 + fn * 16 + cn;
            float bias = bph[i];
            #pragma unroll
            for (int fm = 0; fm < 2; ++fm) {
                int q = q0 + wm * 32 + fm * 16 + r4;
                #pragma unroll
                for (int r = 0; r < 4; ++r) {
                    ushort val = ((q + r) < NQ_) ? f2bf(acc[fm][fn][r] + bias) : (ushort)0;
                    phi_bf[((size_t)((b << 8) + q + r)) * 128 + i] = val;
                }
            }
        }
        return;
    }

    // ---- k2: out[o][n] = Wcomb[o]·xT[n], 128x64 tiles, K=256 ----
    int bx = blockIdx.x;
    int b = bx & 7; int rest = bx >> 3;          // 0..97
    int mt = rest & 1, nt = rest >> 1;           // mt 0..1, nt 0..48
    int o0 = mt * 128, n0 = nt * 64;
    int wm = w >> 1, wn = w & 1;
    int cn = lane & 15, kc = lane >> 4;

    int arow = t >> 1, ach = t & 1;
    const ushort* ga = Wcomb + (size_t)(o0 + arow) * 256 + ach * 8;
    int brow = t >> 2, bch = t & 3;
    const ushort* gb = xT + ((size_t)(b * N_) + n0 + brow) * 256 + bch * 8;
    ushort* la = &Al[arow * 40 + ach * 8];
    ushort* lb = &Bl[brow * 40 + bch * 8];

    f32x4 acc[4][2];
    #pragma unroll
    for (int a = 0; a < 4; ++a)
        #pragma unroll
        for (int bb = 0; bb < 2; ++bb) acc[a][bb] = (f32x4){0.f, 0.f, 0.f, 0.f};

    int am = (wm * 64 + cn) * 40 + kc * 8;
    int bn = (wn * 32 + cn) * 40 + kc * 8;

    uint4 aw0 = *(const uint4*)(ga);
    uint4 aw1 = *(const uint4*)(ga + 16);
    uint4 bw = *(const uint4*)(gb);
    for (int ks = 0; ks < 8; ++ks) {
        __syncthreads();
        *(uint4*)la = aw0;
        *(uint4*)(la + 16) = aw1;
        *(uint4*)lb = bw;
        __syncthreads();
        if (ks + 1 < 8) {
            aw0 = *(const uint4*)(ga + (ks + 1) * 32);
            aw1 = *(const uint4*)(ga + (ks + 1) * 32 + 16);
            bw = *(const uint4*)(gb + (ks + 1) * 32);
        }
        bf16x8 af[4], bfv[2];
        #pragma unroll
        for (int fm = 0; fm < 4; ++fm) af[fm] = *(const bf16x8*)(&Al[am + fm * 16 * 40]);
        #pragma unroll
        for (int fn = 0; fn < 2; ++fn) bfv[fn] = *(const bf16x8*)(&Bl[bn + fn * 16 * 40]);
        #pragma unroll
        for (int fm = 0; fm < 4; ++fm)
            #pragma unroll
            for (int fn = 0; fn < 2; ++fn)
                acc[fm][fn] = __builtin_amdgcn_mfma_f32_16x16x32_bf16(af[fm], bfv[fn], acc[fm][fn], 0, 0, 0);
    }

    int r4 = kc * 4;
    if (mt == 0) {
        #pragma unroll
        for (int fm = 0; fm < 4; ++fm) {
            int ob = wm * 64 + fm * 16 + r4;
            #pragma unroll
            for (int fn = 0; fn < 2; ++fn) {
                int n = n0 + wn * 32 + fn * 16 + cn;
                ushort4 v;
                v.x = f2bf(acc[fm][fn][0] + bth[ob + 0]);
                v.y = f2bf(acc[fm][fn][1] + bth[ob + 1]);
                v.z = f2bf(acc[fm][fn][2] + bth[ob + 2]);
                v.w = f2bf(acc[fm][fn][3] + bth[ob + 3]);
                *(ushort4*)(&thT[((size_t)(b * N_) + n) * 128 + ob]) = v;
            }
        }
    } else {
        #pragma unroll
        for (int fm = 0; fm < 4; ++fm) {
            int og = wm * 64 + fm * 16 + r4;
            #pragma unroll
            for (int fn = 0; fn < 2; ++fn) {
                int n = n0 + wn * 32 + fn * 16 + cn;
                #pragma unroll
                for (int r = 0; r < 4; ++r)
                    gT[((size_t)(b * 128) + og + r) * N_ + n] = f2bf(acc[fm][fn][r] + bg[og + r]);
            }
        }
    }
}

// ================= K3: fused flash attention (r11 config + reg prefetch) =======
// grid 8b * 7qt * 7ksp = 392, block 256 (4 waves); q-tile 32, n-subtiles of 64.
// r12 lesson: splitting work (q or n axis) raises barrier+staging overhead per
// FLOP — regressed both times. This round: keep r11 geometry, add k2-style
// one-iteration register prefetch (loads for s+1 issued during compute of s).
// Loop-carried regs ~75 (yacc16+rs8+kv16+gv16+addr) — no paf, unlike r5's spill.
__global__ __launch_bounds__(256, 2) void k3_flash(
    const ushort* __restrict__ phi_bf, const ushort* __restrict__ thT,
    const ushort* __restrict__ gT, float* __restrict__ y_ws, float* __restrict__ rowsum)
{
    __shared__ ushort Qs[32 * 136];   // phi tile [32q][128k] (8704B)
    __shared__ ushort Kt[64 * 136];   // thT subtile [64n][128k] (17408B)
    __shared__ ushort Gt[128 * 72];   // gT subtile [128i][64n] (18432B)
    __shared__ ushort Ps[32 * 72];    // P [32q][64n] (4608B)  — total 48KB
    int bx = blockIdx.x;
    int b = bx & 7; int rr_ = bx >> 3;           // 0..48
    int qt = rr_ % 7, ksp = rr_ / 7;
    int q0 = qt * 32;
    int nb0 = ksp * 448;
    int t = threadIdx.x;
    int lane = t & 63, w = t >> 6;
    int cn = lane & 15, kc = lane >> 4;

    // stage phi tile once: 512 uint4, 2 per thread
    #pragma unroll
    for (int rr2 = 0; rr2 < 2; ++rr2) {
        int idx = t + rr2 * 256;                 // 0..511
        int q = idx >> 4, ch = idx & 15;
        uint4 v = *(const uint4*)(phi_bf + ((size_t)((b << 8) + q0 + q)) * 128 + ch * 8);
        *(uint4*)(&Qs[q * 136 + ch * 8]) = v;
    }

    int krow = t >> 2, kch = t & 3;
    int grow = t >> 1, gch = t & 1;
    const ushort* gK = thT + ((size_t)(b * N_) + nb0 + krow) * 128 + kch * 8;
    const ushort* gG = gT + ((size_t)(b * 128) + grow) * N_ + nb0 + gch * 8;
    ushort* lK = &Kt[krow * 136 + kch * 8];
    ushort* lG = &Gt[grow * 72 + gch * 8];

    // prefetch s=0
    uint4 kv[4], gv[4];
    #pragma unroll
    for (int it = 0; it < 4; ++it) {
        kv[it] = *(const uint4*)(gK + it * 32);
        gv[it] = *(const uint4*)(gG + it * 16);
    }
    gK += (size_t)64 * 128;
    gG += 64;

    float rs[2][4] = {{0, 0, 0, 0}, {0, 0, 0, 0}};
    f32x4 yacc[2][2];
    #pragma unroll
    for (int a = 0; a < 2; ++a)
        #pragma unroll
        for (int bb = 0; bb < 2; ++bb) yacc[a][bb] = (f32x4){0.f, 0.f, 0.f, 0.f};

    for (int s = 0; s < 7; ++s) {
        __syncthreads();                          // prev iter's Kt/Gt/Ps reads done
        #pragma unroll
        for (int it = 0; it < 4; ++it) {
            *(uint4*)(lK + it * 32) = kv[it];
            *(uint4*)(lG + it * 16) = gv[it];
        }
        __syncthreads();                          // staging (and Qs at s=0) visible
        if (s + 1 < 7) {                          // prefetch s+1 (in flight over compute)
            #pragma unroll
            for (int it = 0; it < 4; ++it) {
                kv[it] = *(const uint4*)(gK + it * 32);
                gv[it] = *(const uint4*)(gG + it * 16);
            }
            gK += (size_t)64 * 128;
            gG += 64;
        }
        f32x4 f0 = (f32x4){0.f, 0.f, 0.f, 0.f};
        f32x4 f1 = (f32x4){0.f, 0.f, 0.f, 0.f};
        #pragma unroll
        for (int k4 = 0; k4 < 4; ++k4) {
            bf16x8 af0 = *(const bf16x8*)(&Qs[cn * 136 + k4 * 32 + kc * 8]);
            bf16x8 af1 = *(const bf16x8*)(&Qs[(16 + cn) * 136 + k4 * 32 + kc * 8]);
            bf16x8 bk = *(const bf16x8*)(&Kt[(w * 16 + cn) * 136 + k4 * 32 + kc * 8]);
            f0 = __builtin_amdgcn_mfma_f32_16x16x32_bf16(af0, bk, f0, 0, 0, 0);
            f1 = __builtin_amdgcn_mfma_f32_16x16x32_bf16(af1, bk, f1, 0, 0, 0);
        }
        #pragma unroll
        for (int r2 = 0; r2 < 4; ++r2) {
            float e0 = __expf(f0[r2]);
            float e1 = __expf(f1[r2]);
            rs[0][r2] += e0; rs[1][r2] += e1;
            Ps[(kc * 4 + r2) * 72 + w * 16 + cn] = f2bf(e0);
            Ps[(16 + kc * 4 + r2) * 72 + w * 16 + cn] = f2bf(e1);
        }
        __syncthreads();                          // Ps visible to all waves
        #pragma unroll
        for (int k2 = 0; k2 < 2; ++k2) {
            bf16x8 pa0 = *(const bf16x8*)(&Ps[cn * 72 + k2 * 32 + kc * 8]);
            bf16x8 pa1 = *(const bf16x8*)(&Ps[(16 + cn) * 72 + k2 * 32 + kc * 8]);
            bf16x8 g0 = *(const bf16x8*)(&Gt[(w * 32 + cn) * 72 + k2 * 32 + kc * 8]);
            bf16x8 g1 = *(const bf16x8*)(&Gt[(w * 32 + 16 + cn) * 72 + k2 * 32 + kc * 8]);
            yacc[0][0] = __builtin_amdgcn_mfma_f32_16x16x32_bf16(pa0, g0, yacc[0][0], 0, 0, 0);
            yacc[0][1] = __builtin_amdgcn_mfma_f32_16x16x32_bf16(pa0, g1, yacc[0][1], 0, 0, 0);
            yacc[1][0] = __builtin_amdgcn_mfma_f32_16x16x32_bf16(pa1, g0, yacc[1][0], 0, 0, 0);
            yacc[1][1] = __builtin_amdgcn_mfma_f32_16x16x32_bf16(pa1, g1, yacc[1][1], 0, 0, 0);
        }
    }

    #pragma unroll
    for (int fm = 0; fm < 2; ++fm) {
        #pragma unroll
        for (int fn = 0; fn < 2; ++fn) {
            int i = w * 32 + fn * 16 + cn;
            #pragma unroll
            for (int r2 = 0; r2 < 4; ++r2) {
                int q = q0 + fm * 16 + kc * 4 + r2;
                if (q < NQ_)
                    atomicAdd(&y_ws[((size_t)(b * NQ_) + q) * 128 + i], yacc[fm][fn][r2]);
            }
        }
    }
    #pragma unroll
    for (int off = 1; off <= 8; off <<= 1) {
        #pragma unroll
        for (int fm = 0; fm < 2; ++fm)
            #pragma unroll
            for (int r2 = 0; r2 < 4; ++r2)
                rs[fm][r2] += __shfl_xor(rs[fm][r2], off);
    }
    if (cn == 0) {
        #pragma unroll
        for (int fm = 0; fm < 2; ++fm)
            #pragma unroll
            for (int r2 = 0; r2 < 4; ++r2)
                atomicAdd(&rowsum[(b << 8) + q0 + fm * 16 + kc * 4 + r2], rs[fm][r2]);
    }
}

// ================= K45: z = BN2((y/rowsum) @ Wz^T + bz); out = upsample(z)+x ===
// grid 8b * 14hq = 112, block 256 (4 waves). GEMM 16q(pad)x256c, K=128 (4 ksteps)
__global__ __launch_bounds__(256) void k45(
    const float* __restrict__ y_ws, const float* __restrict__ rowsum,
    const ushort* __restrict__ Wz_bf,
    const float* __restrict__ bz, const float* __restrict__ g2, const float* __restrict__ b2,
    const float* __restrict__ rm2, const float* __restrict__ rv2,
    const float* __restrict__ x_cnn, float* __restrict__ out)
{
    __shared__ ushort Al[16 * 136];    // y_norm bf16 [16q pad][128i]
    __shared__ ushort Bl[256 * 40];    // Wz slice [256c][32k]
    __shared__ float zs[16 * 260];     // z [16q][256c], padded rows
    int bx = blockIdx.x;
    int b = bx & 7, hq = bx >> 3;      // hq 0..13
    int q0 = hq * 14;
    int t = threadIdx.x;
    int lane = t & 63, w = t >> 6;
    int cn = lane & 15, kc = lane >> 4;

    // stage A: normalize y -> bf16; rows 14,15 zero
    {
        int row = t >> 4, i0 = (t & 15) * 8;
        uint4 aw = make_uint4(0, 0, 0, 0);
        if (row < 14) {
            float inv = 1.0f / rowsum[(b << 8) + q0 + row];
            const float* yp = y_ws + ((size_t)(b * NQ_) + q0 + row) * 128 + i0;
            float4 u = *(const float4*)(yp), v = *(const float4*)(yp + 4);
            aw.x = pack2(u.x * inv, u.y * inv); aw.y = pack2(u.z * inv, u.w * inv);
            aw.z = pack2(v.x * inv, v.y * inv); aw.w = pack2(v.z * inv, v.w * inv);
        }
        *(uint4*)(&Al[row * 136 + i0]) = aw;
    }

    f32x4 acc[4];
    #pragma unroll
    for (int a = 0; a < 4; ++a) acc[a] = (f32x4){0.f, 0.f, 0.f, 0.f};
    int am = cn * 136 + kc * 8;
    int bn = (w * 64 + cn) * 40 + kc * 8;

    #pragma unroll
    for (int ks = 0; ks < 4; ++ks) {
        __syncthreads();   // covers Al at ks=0; Bl reuse after
        {
            const ushort* wp = Wz_bf + (size_t)t * 128 + ks * 32;
            uint4 b0 = *(const uint4*)(wp);
            uint4 b1v = *(const uint4*)(wp + 8);
            *(uint4*)(&Bl[t * 40]) = b0;
            *(uint4*)(&Bl[t * 40 + 8]) = b1v;
        }
        __syncthreads();
        bf16x8 af = *(const bf16x8*)(&Al[am + ks * 32]);
        #pragma unroll
        for (int fc = 0; fc < 4; ++fc) {
            bf16x8 bv = *(const bf16x8*)(&Bl[bn + fc * 16 * 40]);
            acc[fc] = __builtin_amdgcn_mfma_f32_16x16x32_bf16(af, bv, acc[fc], 0, 0, 0);
        }
    }

    // BN2 epilogue -> zs
    #pragma unroll
    for (int fc = 0; fc < 4; ++fc) {
        int c = w * 64 + fc * 16 + cn;
        float inv2 = g2[c] * rsqrtf(rv2[c] + 1e-5f);
        float add2 = b2[c] - rm2[c] * inv2;
        float bzc = bz[c];
        #pragma unroll
        for (int r = 0; r < 4; ++r) {
            int q = kc * 4 + r;
            zs[q * 260 + c] = (acc[fc][r] + bzc) * inv2 + add2;
        }
    }
    __syncthreads();

    // upsample + residual: 224 active threads (16 c-groups x 14 w4)
    if (t < 224) {
        int c4 = t / 14, w4 = t % 14;
        #pragma unroll
        for (int ccg = 0; ccg < 16; ++ccg) {
            int c = c4 * 16 + ccg;
            float z = zs[w4 * 260 + c];
            #pragma unroll
            for (int dh = 0; dh < 4; ++dh) {
                size_t off = ((size_t)(b * C_ + c)) * N_ + (size_t)(hq * 4 + dh) * 56 + w4 * 4;
                float4 xv = *(const float4*)(x_cnn + off);
                *(float4*)(out + off) = make_float4(xv.x + z, xv.y + z, xv.z + z, xv.w + z);
            }
        }
    }
}

extern "C" void kernel_launch(void* const* d_in, const int* in_sizes, int n_in,
                              void* d_out, int out_size, void* d_ws, size_t ws_size,
                              hipStream_t stream) {
    const float* x_t   = (const float*)d_in[0];
    const float* x_cnn = (const float*)d_in[1];
    const float* Wp  = (const float*)d_in[2];
    const float* bp  = (const float*)d_in[3];
    const float* g1  = (const float*)d_in[4];
    const float* b1  = (const float*)d_in[5];
    const float* rm1 = (const float*)d_in[6];
    const float* rv1 = (const float*)d_in[7];
    const float* Wg  = (const float*)d_in[8];
    const float* bg  = (const float*)d_in[9];
    const float* Wth = (const float*)d_in[10];
    const float* bth = (const float*)d_in[11];
    const float* Wph = (const float*)d_in[12];
    const float* bph = (const float*)d_in[13];
    const float* Wz  = (const float*)d_in[14];
    const float* bz  = (const float*)d_in[15];
    const float* g2  = (const float*)d_in[16];
    const float* b2  = (const float*)d_in[17];
    const float* rm2 = (const float*)d_in[18];
    const float* rv2 = (const float*)d_in[19];
    float* out = (float*)d_out;

    char* ws = (char*)d_ws;
    ushort* xT    = (ushort*)(ws);                 // bf16 [8][3136][256] = 12,845,056
    ushort* thT   = (ushort*)(ws + 12845056);      // bf16 [8][3136][128] = 6,422,528
    ushort* gT    = (ushort*)(ws + 19267584);      // bf16 [8][128][3136] = 6,422,528
    ushort* phi   = (ushort*)(ws + 25690112);      // bf16 [8][256][128]  = 524,288
    float*  y_ws  = (float*)(ws + 26214400);       // fp32 [8][196][128]  = 802,816
    ushort* Wcomb = (ushort*)(ws + 27017216);      // bf16 [256][256]     = 131,072
    ushort* Wph_bf= (ushort*)(ws + 27148288);      // bf16 [128][256]     = 65,536
    ushort* Wz_bf = (ushort*)(ws + 27213824);      // bf16 [256][128]     = 65,536
    ushort* xact  = (ushort*)(ws + 27279360);      // bf16 [8*256][256]   = 1,048,576
    float*  rowsum= (float*)(ws + 28327936);       // fp32 [8*256]        = 8,192

    k01<<<dim3(2080), dim3(256), 0, stream>>>(x_cnn, xT, Wth, Wg, Wph, Wz, x_t, Wp,
                                              bp, g1, b1, rm1, rv1,
                                              Wcomb, Wph_bf, Wz_bf, y_ws, rowsum, xact);
    k12<<<dim3(848), dim3(256), 0, stream>>>(Wcomb, bth, bg, xT, thT, gT,
                                             xact, Wph_bf, bph, phi);
    k3_flash<<<dim3(392), dim3(256), 0, stream>>>(phi, thT, gT, y_ws, rowsum);
    k45<<<dim3(112), dim3(256), 0, stream>>>(y_ws, rowsum, Wz_bf, bz, g2, b2, rm2, rv2,
                                             x_cnn, out);
}

// Round 14
// 70.943 us; speedup vs baseline: 1.2802x; 1.2802x over previous
//
#include <hip/hip_runtime.h>
#include <hip/hip_bf16.h>

// Shapes (fixed): B=8, E=768, C=256, CI=128, H=W=14, UP=4 -> H2=W2=56, N=3136, NQ=196
#define B_ 8
#define E_ 768
#define C_ 256
#define CI_ 128
#define NQ_ 196
#define N_ 3136

typedef short bf16x8 __attribute__((ext_vector_type(8)));
typedef float f32x4 __attribute__((ext_vector_type(4)));

__device__ __forceinline__ ushort f2bf(float x) {
    union { float f; uint u; } v; v.f = x;
    uint r = v.u + 0x7FFFu + ((v.u >> 16) & 1u);   // RNE
    return (ushort)(r >> 16);
}
__device__ __forceinline__ uint pack2(float a, float b) {
    return (uint)f2bf(a) | ((uint)f2bf(b) << 16);
}

// ================= K01: transpose (0..1567) | weight conv+zero (1568..1823)
//                        | k1a proj with inline Wp conversion (1824..2079) ======
__global__ __launch_bounds__(256) void k01(
    const float* __restrict__ x_cnn, ushort* __restrict__ xT,
    const float* __restrict__ Wth, const float* __restrict__ Wg,
    const float* __restrict__ Wph, const float* __restrict__ Wz,
    const float* __restrict__ x_t, const float* __restrict__ Wp,
    const float* __restrict__ bp, const float* __restrict__ g1, const float* __restrict__ b1,
    const float* __restrict__ rm1, const float* __restrict__ rv1,
    ushort* __restrict__ Wcomb, ushort* __restrict__ Wph_bf, ushort* __restrict__ Wz_bf,
    float* __restrict__ y_ws, float* __restrict__ rowsum, ushort* __restrict__ xact)
{
    __shared__ float Xs[64][68];
    __shared__ ushort Al[32 * 40];
    __shared__ ushort Bl[64 * 40];
    int bx = blockIdx.x;
    int t = threadIdx.x;

    if (bx >= 1824) {
        // ---- k1a: xact = relu(BN(x_t @ Wp^T)), 32q x 64c tiles, K=768 ----
        int bx2 = bx - 1824;
        int b = bx2 & 7; int rest = bx2 >> 3;
        int mt = rest & 7, nt = rest >> 3;
        int q0 = mt * 32, c0 = nt * 64;
        int lane = t & 63, w = t >> 6;

        int arow = t >> 3, ac4 = t & 7;
        bool arow_ok = (q0 + arow) < NQ_;
        const float* gax = x_t + (size_t)b * 197 * 768 + (size_t)(1 + q0 + arow) * 768 + ac4 * 4;
        int brow = t >> 2, bc = t & 3;
        const float* gbf = Wp + (size_t)(c0 + brow) * 768 + bc * 8;
        float binv = g1[c0 + brow] * rsqrtf(rv1[c0 + brow] + 1e-6f);
        ushort* la = &Al[arow * 40 + ac4 * 4];
        ushort* lb = &Bl[brow * 40 + bc * 8];

        f32x4 acc0 = (f32x4){0.f, 0.f, 0.f, 0.f};
        f32x4 acc1 = (f32x4){0.f, 0.f, 0.f, 0.f};
        int am = (lane & 15) * 40 + (lane >> 4) * 8;
        int bn = (w * 16 + (lane & 15)) * 40 + (lane >> 4) * 8;

        uint2 aw; aw.x = 0; aw.y = 0;
        if (arow_ok) { float4 x0 = *(const float4*)(gax); aw.x = pack2(x0.x, x0.y); aw.y = pack2(x0.z, x0.w); }
        uint4 bw;
        {
            float4 u = *(const float4*)(gbf), v = *(const float4*)(gbf + 4);
            bw.x = pack2(u.x * binv, u.y * binv); bw.y = pack2(u.z * binv, u.w * binv);
            bw.z = pack2(v.x * binv, v.y * binv); bw.w = pack2(v.z * binv, v.w * binv);
        }

        for (int ks = 0; ks < 24; ++ks) {
            __syncthreads();
            *(uint2*)la = aw;
            *(uint4*)lb = bw;
            __syncthreads();
            if (ks + 1 < 24) {
                aw.x = 0; aw.y = 0;
                if (arow_ok) {
                    float4 x0 = *(const float4*)(gax + (ks + 1) * 32);
                    aw.x = pack2(x0.x, x0.y); aw.y = pack2(x0.z, x0.w);
                }
                float4 u = *(const float4*)(gbf + (ks + 1) * 32);
                float4 v = *(const float4*)(gbf + (ks + 1) * 32 + 4);
                bw.x = pack2(u.x * binv, u.y * binv); bw.y = pack2(u.z * binv, u.w * binv);
                bw.z = pack2(v.x * binv, v.y * binv); bw.w = pack2(v.z * binv, v.w * binv);
            }
            bf16x8 af0 = *(const bf16x8*)(&Al[am]);
            bf16x8 af1 = *(const bf16x8*)(&Al[am + 16 * 40]);
            bf16x8 bfv = *(const bf16x8*)(&Bl[bn]);
            acc0 = __builtin_amdgcn_mfma_f32_16x16x32_bf16(af0, bfv, acc0, 0, 0, 0);
            acc1 = __builtin_amdgcn_mfma_f32_16x16x32_bf16(af1, bfv, acc1, 0, 0, 0);
        }

        int r4 = (lane >> 4) * 4;
        int cn = lane & 15;
        int c = c0 + w * 16 + cn;
        float inv1 = g1[c] * rsqrtf(rv1[c] + 1e-6f);
        float badd = bp[c] * inv1 + b1[c] - rm1[c] * inv1;
        #pragma unroll
        for (int r = 0; r < 4; ++r) {
            float v0 = fmaxf(acc0[r] + badd, 0.0f);
            float v1 = fmaxf(acc1[r] + badd, 0.0f);
            xact[((size_t)((b << 8) + q0 + r4 + r)) * 256 + c] = f2bf(v0);
            xact[((size_t)((b << 8) + q0 + 16 + r4 + r)) * 256 + c] = f2bf(v1);
        }
        return;
    }
    if (bx >= 1568) {
        // ---- weight conv + zeroing ----
        int idx = (bx - 1568) * 256 + t;          // 0..65535
        int o = idx >> 8, c = idx & 255;
        float v = (o < 128) ? Wth[o * 256 + c] : Wg[(o - 128) * 256 + c];
        Wcomb[idx] = f2bf(v);
        if (idx < 32768) Wph_bf[idx] = f2bf(Wph[idx]);
        if (idx < 32768) Wz_bf[idx] = f2bf(Wz[idx]);
        if (idx < 2048) rowsum[idx] = 0.0f;
        for (int i = idx; i < B_ * NQ_ * CI_; i += 65536) y_ws[i] = 0.0f;
        return;
    }
    // ---- x_cnn transpose -> xT bf16 ----
    int b = bx & 7; int rest = bx >> 3;
    int ct = rest & 3, nt = rest >> 2;            // ct 0..3, nt 0..48
    int c0 = ct * 64, n0 = nt * 64;
    #pragma unroll
    for (int rr = 0; rr < 4; ++rr) {
        int idx = t + rr * 256;                   // 0..1023
        int c = idx >> 4, n4 = idx & 15;
        float4 v = *(const float4*)(x_cnn + ((size_t)(b * C_) + c0 + c) * N_ + n0 + n4 * 4);
        *(float4*)(&Xs[c][n4 * 4]) = v;
    }
    __syncthreads();
    int n = t & 63, cc = t >> 6;                  // cc 0..3 (16 c each)
    ushort vals[16];
    #pragma unroll
    for (int j = 0; j < 16; ++j)
        vals[j] = f2bf(Xs[cc * 16 + j][n]);
    ushort* outp = xT + ((size_t)(b * N_) + n0 + n) * 256 + c0 + cc * 16;
    *(uint4*)(outp) = *(const uint4*)(&vals[0]);
    *(uint4*)(outp + 8) = *(const uint4*)(&vals[8]);
}

// ================= K12: k2 theta/g GEMM (0..783) | k1b phi GEMM (784..847) =====
__global__ __launch_bounds__(256) void k12(
    const ushort* __restrict__ Wcomb, const float* __restrict__ bth, const float* __restrict__ bg,
    const ushort* __restrict__ xT, ushort* __restrict__ thT, ushort* __restrict__ gT,
    const ushort* __restrict__ xact, const ushort* __restrict__ Wph_bf,
    const float* __restrict__ bph, ushort* __restrict__ phi_bf)
{
    __shared__ ushort Al[128 * 40];
    __shared__ ushort Bl[64 * 40];
    int t = threadIdx.x;
    int lane = t & 63, w = t >> 6;

    if (blockIdx.x >= 784) {
        // ---- k1b: phi = xact @ Wph^T + bph, 64q x 64i tiles, K=256 ----
        int bx2 = blockIdx.x - 784;
        int b = bx2 & 7; int rest = bx2 >> 3;
        int mt = rest & 3, nt = rest >> 2;
        int q0 = mt * 64, i0 = nt * 64;
        int wm = w >> 1, wn = w & 1;
        int row = t >> 2, chunk = t & 3;

        const ushort* ga = xact + ((size_t)((b << 8) + q0 + row)) * 256 + chunk * 8;
        const ushort* gb = Wph_bf + (size_t)(i0 + row) * 256 + chunk * 8;
        ushort* la = &Al[row * 40 + chunk * 8];
        ushort* lb = &Bl[row * 40 + chunk * 8];

        f32x4 acc[2][2];
        #pragma unroll
        for (int a = 0; a < 2; ++a)
            #pragma unroll
            for (int bb = 0; bb < 2; ++bb) acc[a][bb] = (f32x4){0.f, 0.f, 0.f, 0.f};

        int am = (wm * 32 + (lane & 15)) * 40 + (lane >> 4) * 8;
        int bn = (wn * 32 + (lane & 15)) * 40 + (lane >> 4) * 8;

        uint4 aw = *(const uint4*)(ga);
        uint4 bw = *(const uint4*)(gb);
        for (int ks = 0; ks < 8; ++ks) {
            __syncthreads();
            *(uint4*)la = aw;
            *(uint4*)lb = bw;
            __syncthreads();
            if (ks + 1 < 8) {
                aw = *(const uint4*)(ga + (ks + 1) * 32);
                bw = *(const uint4*)(gb + (ks + 1) * 32);
            }
            bf16x8 af[2], bfv[2];
            #pragma unroll
            for (int fm = 0; fm < 2; ++fm) af[fm] = *(const bf16x8*)(&Al[am + fm * 16 * 40]);
            #pragma unroll
            for (int fn = 0; fn < 2; ++fn) bfv[fn] = *(const bf16x8*)(&Bl[bn + fn * 16 * 40]);
            #pragma unroll
            for (int fm = 0; fm < 2; ++fm)
                #pragma unroll
                for (int fn = 0; fn < 2; ++fn)
                    acc[fm][fn] = __builtin_amdgcn_mfma_f32_16x16x32_bf16(af[fm], bfv[fn], acc[fm][fn], 0, 0, 0);
        }

        int r4 = (lane >> 4) * 4;
        int cn = lane & 15;
        #pragma unroll
        for (int fn = 0; fn < 2; ++fn) {
            int i = i0 + wn * 32 + fn * 16 + cn;
            float bias = bph[i];
            #pragma unroll
            for (int fm = 0; fm < 2; ++fm) {
                int q = q0 + wm * 32 + fm * 16 + r4;
                #pragma unroll
                for (int r = 0; r < 4; ++r) {
                    ushort val = ((q + r) < NQ_) ? f2bf(acc[fm][fn][r] + bias) : (ushort)0;
                    phi_bf[((size_t)((b << 8) + q + r)) * 128 + i] = val;
                }
            }
        }
        return;
    }

    // ---- k2: out[o][n] = Wcomb[o]·xT[n], 128x64 tiles, K=256 ----
    int bx = blockIdx.x;
    int b = bx & 7; int rest = bx >> 3;          // 0..97
    int mt = rest & 1, nt = rest >> 1;           // mt 0..1, nt 0..48
    int o0 = mt * 128, n0 = nt * 64;
    int wm = w >> 1, wn = w & 1;
    int cn = lane & 15, kc = lane >> 4;

    int arow = t >> 1, ach = t & 1;
    const ushort* ga = Wcomb + (size_t)(o0 + arow) * 256 + ach * 8;
    int brow = t >> 2, bch = t & 3;
    const ushort* gb = xT + ((size_t)(b * N_) + n0 + brow) * 256 + bch * 8;
    ushort* la = &Al[arow * 40 + ach * 8];
    ushort* lb = &Bl[brow * 40 + bch * 8];

    f32x4 acc[4][2];
    #pragma unroll
    for (int a = 0; a < 4; ++a)
        #pragma unroll
        for (int bb = 0; bb < 2; ++bb) acc[a][bb] = (f32x4){0.f, 0.f, 0.f, 0.f};

    int am = (wm * 64 + cn) * 40 + kc * 8;
    int bn = (wn * 32 + cn) * 40 + kc * 8;

    uint4 aw0 = *(const uint4*)(ga);
    uint4 aw1 = *(const uint4*)(ga + 16);
    uint4 bw = *(const uint4*)(gb);
    for (int ks = 0; ks < 8; ++ks) {
        __syncthreads();
        *(uint4*)la = aw0;
        *(uint4*)(la + 16) = aw1;
        *(uint4*)lb = bw;
        __syncthreads();
        if (ks + 1 < 8) {
            aw0 = *(const uint4*)(ga + (ks + 1) * 32);
            aw1 = *(const uint4*)(ga + (ks + 1) * 32 + 16);
            bw = *(const uint4*)(gb + (ks + 1) * 32);
        }
        bf16x8 af[4], bfv[2];
        #pragma unroll
        for (int fm = 0; fm < 4; ++fm) af[fm] = *(const bf16x8*)(&Al[am + fm * 16 * 40]);
        #pragma unroll
        for (int fn = 0; fn < 2; ++fn) bfv[fn] = *(const bf16x8*)(&Bl[bn + fn * 16 * 40]);
        #pragma unroll
        for (int fm = 0; fm < 4; ++fm)
            #pragma unroll
            for (int fn = 0; fn < 2; ++fn)
                acc[fm][fn] = __builtin_amdgcn_mfma_f32_16x16x32_bf16(af[fm], bfv[fn], acc[fm][fn], 0, 0, 0);
    }

    int r4 = kc * 4;
    if (mt == 0) {
        #pragma unroll
        for (int fm = 0; fm < 4; ++fm) {
            int ob = wm * 64 + fm * 16 + r4;
            #pragma unroll
            for (int fn = 0; fn < 2; ++fn) {
                int n = n0 + wn * 32 + fn * 16 + cn;
                ushort4 v;
                v.x = f2bf(acc[fm][fn][0] + bth[ob + 0]);
                v.y = f2bf(acc[fm][fn][1] + bth[ob + 1]);
                v.z = f2bf(acc[fm][fn][2] + bth[ob + 2]);
                v.w = f2bf(acc[fm][fn][3] + bth[ob + 3]);
                *(ushort4*)(&thT[((size_t)(b * N_) + n) * 128 + ob]) = v;
            }
        }
    } else {
        #pragma unroll
        for (int fm = 0; fm < 4; ++fm) {
            int og = wm * 64 + fm * 16 + r4;
            #pragma unroll
            for (int fn = 0; fn < 2; ++fn) {
                int n = n0 + wn * 32 + fn * 16 + cn;
                #pragma unroll
                for (int r = 0; r < 4; ++r)
                    gT[((size_t)(b * 128) + og + r) * N_ + n] = f2bf(acc[fm][fn][r] + bg[og + r]);
            }
        }
    }
}

// ================= K3: fused flash attention — phase-swapped staging ===========
// grid 8b * 7qt * 7ksp = 392, block 256 (4 waves); q-tile 32, n-subtiles of 64.
// r5/r13 lesson: regs across barriers spill. Fix: QK reads only Kt, PV reads
// only Gt, so stage Gt(s) DURING the QK phase and Kt(s+1) DURING the PV phase —
// staging load+ds_write is transient within one barrier interval, overlapped
// with 8 MFMAs. 2 barriers/iter (was 3), same 48KB LDS, no cross-barrier regs.
__global__ __launch_bounds__(256, 2) void k3_flash(
    const ushort* __restrict__ phi_bf, const ushort* __restrict__ thT,
    const ushort* __restrict__ gT, float* __restrict__ y_ws, float* __restrict__ rowsum)
{
    __shared__ ushort Qs[32 * 136];   // phi tile [32q][128k] (8704B)
    __shared__ ushort Kt[64 * 136];   // thT subtile [64n][128k] (17408B)
    __shared__ ushort Gt[128 * 72];   // gT subtile [128i][64n] (18432B)
    __shared__ ushort Ps[32 * 72];    // P [32q][64n] (4608B)  — total 48KB
    int bx = blockIdx.x;
    int b = bx & 7; int rr_ = bx >> 3;           // 0..48
    int qt = rr_ % 7, ksp = rr_ / 7;
    int q0 = qt * 32;
    int nb0 = ksp * 448;
    int t = threadIdx.x;
    int lane = t & 63, w = t >> 6;
    int cn = lane & 15, kc = lane >> 4;

    int krow = t >> 2, kch = t & 3;
    int grow = t >> 1, gch = t & 1;
    const ushort* gK = thT + ((size_t)(b * N_) + nb0 + krow) * 128 + kch * 8;
    const ushort* gG = gT + ((size_t)(b * 128) + grow) * N_ + nb0 + gch * 8;
    ushort* lK = &Kt[krow * 136 + kch * 8];
    ushort* lG = &Gt[grow * 72 + gch * 8];

    // prologue: stage phi tile + Kt(0)
    #pragma unroll
    for (int rr2 = 0; rr2 < 2; ++rr2) {
        int idx = t + rr2 * 256;                 // 0..511
        int q = idx >> 4, ch = idx & 15;
        uint4 v = *(const uint4*)(phi_bf + ((size_t)((b << 8) + q0 + q)) * 128 + ch * 8);
        *(uint4*)(&Qs[q * 136 + ch * 8]) = v;
    }
    {
        uint4 kv[4];
        #pragma unroll
        for (int it = 0; it < 4; ++it) kv[it] = *(const uint4*)(gK + it * 32);
        #pragma unroll
        for (int it = 0; it < 4; ++it) *(uint4*)(lK + it * 32) = kv[it];
    }
    __syncthreads();                              // Qs + Kt(0) visible

    float rs[2][4] = {{0, 0, 0, 0}, {0, 0, 0, 0}};
    f32x4 yacc[2][2];
    #pragma unroll
    for (int a = 0; a < 2; ++a)
        #pragma unroll
        for (int bb = 0; bb < 2; ++bb) yacc[a][bb] = (f32x4){0.f, 0.f, 0.f, 0.f};

    for (int s = 0; s < 7; ++s) {
        // ---- I1: stage Gt(s) overlapped with QK on Kt(s) ----
        {
            uint4 gv[4];
            #pragma unroll
            for (int it = 0; it < 4; ++it) gv[it] = *(const uint4*)(gG + it * 16);
            #pragma unroll
            for (int it = 0; it < 4; ++it) *(uint4*)(lG + it * 16) = gv[it];
        }
        gG += 64;
        f32x4 f0 = (f32x4){0.f, 0.f, 0.f, 0.f};
        f32x4 f1 = (f32x4){0.f, 0.f, 0.f, 0.f};
        #pragma unroll
        for (int k4 = 0; k4 < 4; ++k4) {
            bf16x8 af0 = *(const bf16x8*)(&Qs[cn * 136 + k4 * 32 + kc * 8]);
            bf16x8 af1 = *(const bf16x8*)(&Qs[(16 + cn) * 136 + k4 * 32 + kc * 8]);
            bf16x8 bk = *(const bf16x8*)(&Kt[(w * 16 + cn) * 136 + k4 * 32 + kc * 8]);
            f0 = __builtin_amdgcn_mfma_f32_16x16x32_bf16(af0, bk, f0, 0, 0, 0);
            f1 = __builtin_amdgcn_mfma_f32_16x16x32_bf16(af1, bk, f1, 0, 0, 0);
        }
        #pragma unroll
        for (int r2 = 0; r2 < 4; ++r2) {
            float e0 = __expf(f0[r2]);
            float e1 = __expf(f1[r2]);
            rs[0][r2] += e0; rs[1][r2] += e1;
            Ps[(kc * 4 + r2) * 72 + w * 16 + cn] = f2bf(e0);
            Ps[(16 + kc * 4 + r2) * 72 + w * 16 + cn] = f2bf(e1);
        }
        __syncthreads();                          // syncA: Ps + Gt(s) visible
        // ---- I2: stage Kt(s+1) overlapped with PV on Gt(s) ----
        if (s + 1 < 7) {
            gK += (size_t)64 * 128;
            uint4 kv[4];
            #pragma unroll
            for (int it = 0; it < 4; ++it) kv[it] = *(const uint4*)(gK + it * 32);
            #pragma unroll
            for (int it = 0; it < 4; ++it) *(uint4*)(lK + it * 32) = kv[it];
        }
        #pragma unroll
        for (int k2 = 0; k2 < 2; ++k2) {
            bf16x8 pa0 = *(const bf16x8*)(&Ps[cn * 72 + k2 * 32 + kc * 8]);
            bf16x8 pa1 = *(const bf16x8*)(&Ps[(16 + cn) * 72 + k2 * 32 + kc * 8]);
            bf16x8 g0 = *(const bf16x8*)(&Gt[(w * 32 + cn) * 72 + k2 * 32 + kc * 8]);
            bf16x8 g1 = *(const bf16x8*)(&Gt[(w * 32 + 16 + cn) * 72 + k2 * 32 + kc * 8]);
            yacc[0][0] = __builtin_amdgcn_mfma_f32_16x16x32_bf16(pa0, g0, yacc[0][0], 0, 0, 0);
            yacc[0][1] = __builtin_amdgcn_mfma_f32_16x16x32_bf16(pa0, g1, yacc[0][1], 0, 0, 0);
            yacc[1][0] = __builtin_amdgcn_mfma_f32_16x16x32_bf16(pa1, g0, yacc[1][0], 0, 0, 0);
            yacc[1][1] = __builtin_amdgcn_mfma_f32_16x16x32_bf16(pa1, g1, yacc[1][1], 0, 0, 0);
        }
        __syncthreads();                          // syncB: Kt(s+1) visible; Ps/Gt readers done
    }

    #pragma unroll
    for (int fm = 0; fm < 2; ++fm) {
        #pragma unroll
        for (int fn = 0; fn < 2; ++fn) {
            int i = w * 32 + fn * 16 + cn;
            #pragma unroll
            for (int r2 = 0; r2 < 4; ++r2) {
                int q = q0 + fm * 16 + kc * 4 + r2;
                if (q < NQ_)
                    atomicAdd(&y_ws[((size_t)(b * NQ_) + q) * 128 + i], yacc[fm][fn][r2]);
            }
        }
    }
    #pragma unroll
    for (int off = 1; off <= 8; off <<= 1) {
        #pragma unroll
        for (int fm = 0; fm < 2; ++fm)
            #pragma unroll
            for (int r2 = 0; r2 < 4; ++r2)
                rs[fm][r2] += __shfl_xor(rs[fm][r2], off);
    }
    if (cn == 0) {
        #pragma unroll
        for (int fm = 0; fm < 2; ++fm)
            #pragma unroll
            for (int r2 = 0; r2 < 4; ++r2)
                atomicAdd(&rowsum[(b << 8) + q0 + fm * 16 + kc * 4 + r2], rs[fm][r2]);
    }
}

// ================= K45: z = BN2((y/rowsum) @ Wz^T + bz); out = upsample(z)+x ===
// grid 8b * 14hq = 112, block 256 (4 waves). GEMM 16q(pad)x256c, K=128 (4 ksteps)
__global__ __launch_bounds__(256) void k45(
    const float* __restrict__ y_ws, const float* __restrict__ rowsum,
    const ushort* __restrict__ Wz_bf,
    const float* __restrict__ bz, const float* __restrict__ g2, const float* __restrict__ b2,
    const float* __restrict__ rm2, const float* __restrict__ rv2,
    const float* __restrict__ x_cnn, float* __restrict__ out)
{
    __shared__ ushort Al[16 * 136];    // y_norm bf16 [16q pad][128i]
    __shared__ ushort Bl[256 * 40];    // Wz slice [256c][32k]
    __shared__ float zs[16 * 260];     // z [16q][256c], padded rows
    int bx = blockIdx.x;
    int b = bx & 7, hq = bx >> 3;      // hq 0..13
    int q0 = hq * 14;
    int t = threadIdx.x;
    int lane = t & 63, w = t >> 6;
    int cn = lane & 15, kc = lane >> 4;

    // stage A: normalize y -> bf16; rows 14,15 zero
    {
        int row = t >> 4, i0 = (t & 15) * 8;
        uint4 aw = make_uint4(0, 0, 0, 0);
        if (row < 14) {
            float inv = 1.0f / rowsum[(b << 8) + q0 + row];
            const float* yp = y_ws + ((size_t)(b * NQ_) + q0 + row) * 128 + i0;
            float4 u = *(const float4*)(yp), v = *(const float4*)(yp + 4);
            aw.x = pack2(u.x * inv, u.y * inv); aw.y = pack2(u.z * inv, u.w * inv);
            aw.z = pack2(v.x * inv, v.y * inv); aw.w = pack2(v.z * inv, v.w * inv);
        }
        *(uint4*)(&Al[row * 136 + i0]) = aw;
    }

    f32x4 acc[4];
    #pragma unroll
    for (int a = 0; a < 4; ++a) acc[a] = (f32x4){0.f, 0.f, 0.f, 0.f};
    int am = cn * 136 + kc * 8;
    int bn = (w * 64 + cn) * 40 + kc * 8;

    #pragma unroll
    for (int ks = 0; ks < 4; ++ks) {
        __syncthreads();   // covers Al at ks=0; Bl reuse after
        {
            const ushort* wp = Wz_bf + (size_t)t * 128 + ks * 32;
            uint4 b0 = *(const uint4*)(wp);
            uint4 b1v = *(const uint4*)(wp + 8);
            *(uint4*)(&Bl[t * 40]) = b0;
            *(uint4*)(&Bl[t * 40 + 8]) = b1v;
        }
        __syncthreads();
        bf16x8 af = *(const bf16x8*)(&Al[am + ks * 32]);
        #pragma unroll
        for (int fc = 0; fc < 4; ++fc) {
            bf16x8 bv = *(const bf16x8*)(&Bl[bn + fc * 16 * 40]);
            acc[fc] = __builtin_amdgcn_mfma_f32_16x16x32_bf16(af, bv, acc[fc], 0, 0, 0);
        }
    }

    // BN2 epilogue -> zs
    #pragma unroll
    for (int fc = 0; fc < 4; ++fc) {
        int c = w * 64 + fc * 16 + cn;
        float inv2 = g2[c] * rsqrtf(rv2[c] + 1e-5f);
        float add2 = b2[c] - rm2[c] * inv2;
        float bzc = bz[c];
        #pragma unroll
        for (int r = 0; r < 4; ++r) {
            int q = kc * 4 + r;
            zs[q * 260 + c] = (acc[fc][r] + bzc) * inv2 + add2;
        }
    }
    __syncthreads();

    // upsample + residual: 224 active threads (16 c-groups x 14 w4)
    if (t < 224) {
        int c4 = t / 14, w4 = t % 14;
        #pragma unroll
        for (int ccg = 0; ccg < 16; ++ccg) {
            int c = c4 * 16 + ccg;
            float z = zs[w4 * 260 + c];
            #pragma unroll
            for (int dh = 0; dh < 4; ++dh) {
                size_t off = ((size_t)(b * C_ + c)) * N_ + (size_t)(hq * 4 + dh) * 56 + w4 * 4;
                float4 xv = *(const float4*)(x_cnn + off);
                *(float4*)(out + off) = make_float4(xv.x + z, xv.y + z, xv.z + z, xv.w + z);
            }
        }
    }
}

extern "C" void kernel_launch(void* const* d_in, const int* in_sizes, int n_in,
                              void* d_out, int out_size, void* d_ws, size_t ws_size,
                              hipStream_t stream) {
    const float* x_t   = (const float*)d_in[0];
    const float* x_cnn = (const float*)d_in[1];
    const float* Wp  = (const float*)d_in[2];
    const float* bp  = (const float*)d_in[3];
    const float* g1  = (const float*)d_in[4];
    const float* b1  = (const float*)d_in[5];
    const float* rm1 = (const float*)d_in[6];
    const float* rv1 = (const float*)d_in[7];
    const float* Wg  = (const float*)d_in[8];
    const float* bg  = (const float*)d_in[9];
    const float* Wth = (const float*)d_in[10];
    const float* bth = (const float*)d_in[11];
    const float* Wph = (const float*)d_in[12];
    const float* bph = (const float*)d_in[13];
    const float* Wz  = (const float*)d_in[14];
    const float* bz  = (const float*)d_in[15];
    const float* g2  = (const float*)d_in[16];
    const float* b2  = (const float*)d_in[17];
    const float* rm2 = (const float*)d_in[18];
    const float* rv2 = (const float*)d_in[19];
    float* out = (float*)d_out;

    char* ws = (char*)d_ws;
    ushort* xT    = (ushort*)(ws);                 // bf16 [8][3136][256] = 12,845,056
    ushort* thT   = (ushort*)(ws + 12845056);      // bf16 [8][3136][128] = 6,422,528
    ushort* gT    = (ushort*)(ws + 19267584);      // bf16 [8][128][3136] = 6,422,528
    ushort* phi   = (ushort*)(ws + 25690112);      // bf16 [8][256][128]  = 524,288
    float*  y_ws  = (float*)(ws + 26214400);       // fp32 [8][196][128]  = 802,816
    ushort* Wcomb = (ushort*)(ws + 27017216);      // bf16 [256][256]     = 131,072
    ushort* Wph_bf= (ushort*)(ws + 27148288);      // bf16 [128][256]     = 65,536
    ushort* Wz_bf = (ushort*)(ws + 27213824);      // bf16 [256][128]     = 65,536
    ushort* xact  = (ushort*)(ws + 27279360);      // bf16 [8*256][256]   = 1,048,576
    float*  rowsum= (float*)(ws + 28327936);       // fp32 [8*256]        = 8,192

    k01<<<dim3(2080), dim3(256), 0, stream>>>(x_cnn, xT, Wth, Wg, Wph, Wz, x_t, Wp,
                                              bp, g1, b1, rm1, rv1,
                                              Wcomb, Wph_bf, Wz_bf, y_ws, rowsum, xact);
    k12<<<dim3(848), dim3(256), 0, stream>>>(Wcomb, bth, bg, xT, thT, gT,
                                             xact, Wph_bf, bph, phi);
    k3_flash<<<dim3(392), dim3(256), 0, stream>>>(phi, thT, gT, y_ws, rowsum);
    k45<<<dim3(112), dim3(256), 0, stream>>>(y_ws, rowsum, Wz_bf, bz, g2, b2, rm2, rv2,
                                             x_cnn, out);
}